// Round 1
// baseline (214.580 us; speedup 1.0000x reference)
//
#include <hip/hip_runtime.h>
#include <hip/hip_bf16.h>

typedef __bf16 bf16;
typedef __bf16 bf16x4 __attribute__((ext_vector_type(4)));
typedef __bf16 bf16x8 __attribute__((ext_vector_type(8)));
typedef float f32x4 __attribute__((ext_vector_type(4)));

#define D 256          // embed dim
#define NHEAD 8
#define HD 32          // head dim
#define NB_ 8
#define LQ_ 256
#define LS_ 4096
#define MQ (NB_ * LQ_)   // 2048
#define MS (NB_ * LS_)   // 32768

// softmax scale folded into Q projection: hd^-0.5 * log2(e)
#define QSCALE 0.25500527f

// ---------------------------------------------------------------------------
// Kernel 1: cast in_proj_w (768x256) ++ out_w (256x256) to bf16 (contiguous)
// ---------------------------------------------------------------------------
__global__ __launch_bounds__(256) void cast_weights(
    const float* __restrict__ w_in, const float* __restrict__ w_out,
    bf16* __restrict__ wb)
{
    const int idx = blockIdx.x * 256 + threadIdx.x;   // float4 index, 65536 total
    const int n_in4 = (768 * 256) / 4;                 // 49152
    float4 v;
    if (idx < n_in4) v = ((const float4*)w_in)[idx];
    else             v = ((const float4*)w_out)[idx - n_in4];
    bf16x4 o;
    o[0] = (bf16)v.x; o[1] = (bf16)v.y; o[2] = (bf16)v.z; o[3] = (bf16)v.w;
    *(bf16x4*)&wb[(size_t)idx * 4] = o;
}

// ---------------------------------------------------------------------------
// Kernel 2/3: input projection GEMM.  C[m][n] = sum_d A[m][d] * W[n][d] + b[n]
// A = x (+ pe), cast to bf16 on the fly.  Tile 128x128, BK=64, 4 waves (2x2).
// IS_Q: grid (2, 16)  -> Q proj (rows 0..255 of in_proj_w), scaled output
// else: grid (4, 256) -> by 0,1 = K proj (+pe, W rows 256..511)
//                        by 2,3 = V proj (no pe, W rows 512..767)
// ---------------------------------------------------------------------------
template<bool IS_Q>
__global__ __launch_bounds__(256) void proj_kernel(
    const float* __restrict__ x, const float* __restrict__ pe,
    const bf16* __restrict__ wb, const float* __restrict__ bias,
    bf16* __restrict__ outK, bf16* __restrict__ outV, float scale)
{
    __shared__ bf16 As[128][72];
    __shared__ bf16 Bs[128][72];
    const int tid = threadIdx.x;
    const int lane = tid & 63, wid = tid >> 6;
    const int wm = wid >> 1, wn = wid & 1;

    const int by = blockIdx.x;
    const int mblk = blockIdx.y;

    bool addpe; int wrow0, nblk; bf16* out;
    if (IS_Q) { addpe = true; wrow0 = 0; nblk = by; out = outK; }
    else {
        const bool isK = (by < 2);
        addpe = isK; wrow0 = isK ? 256 : 512; nblk = by & 1;
        out = isK ? outK : outV;
    }

    f32x4 acc[4][4];
    #pragma unroll
    for (int i = 0; i < 4; ++i)
        #pragma unroll
        for (int j = 0; j < 4; ++j) acc[i][j] = (f32x4){0.f, 0.f, 0.f, 0.f};

    const size_t arow0 = (size_t)mblk * 128;

    for (int kk = 0; kk < 4; ++kk) {
        const int d0 = kk * 64;
        // ---- stage A: 128 rows x 64 cols f32 -> bf16, fully coalesced
        #pragma unroll
        for (int i = 0; i < 8; ++i) {
            const int idx = i * 256 + tid;       // 0..2047 float4 chunks
            const int r = idx >> 4, c = (idx & 15) * 4;
            const size_t g = (arow0 + r) * D + d0 + c;
            float4 v = *(const float4*)&x[g];
            if (addpe) {
                const float4 p = *(const float4*)&pe[g];
                v.x += p.x; v.y += p.y; v.z += p.z; v.w += p.w;
            }
            bf16x4 o;
            o[0] = (bf16)v.x; o[1] = (bf16)v.y; o[2] = (bf16)v.z; o[3] = (bf16)v.w;
            *(bf16x4*)&As[r][c] = o;
        }
        // ---- stage B (weights, already bf16): 128 rows x 64 cols
        #pragma unroll
        for (int i = 0; i < 4; ++i) {
            const int idx = i * 256 + tid;       // 0..1023 16B chunks
            const int r = idx >> 3, c = (idx & 7) * 8;
            *(bf16x8*)&Bs[r][c] =
                *(const bf16x8*)&wb[(size_t)(wrow0 + nblk * 128 + r) * D + d0 + c];
        }
        __syncthreads();

        #pragma unroll
        for (int h2 = 0; h2 < 2; ++h2) {
            const int ko = h2 * 32 + (lane >> 4) * 8;
            bf16x8 af[4], bfr[4];
            #pragma unroll
            for (int i = 0; i < 4; ++i)
                af[i] = *(const bf16x8*)&As[wm * 64 + i * 16 + (lane & 15)][ko];
            #pragma unroll
            for (int j = 0; j < 4; ++j)
                bfr[j] = *(const bf16x8*)&Bs[wn * 64 + j * 16 + (lane & 15)][ko];
            #pragma unroll
            for (int i = 0; i < 4; ++i)
                #pragma unroll
                for (int j = 0; j < 4; ++j)
                    acc[i][j] = __builtin_amdgcn_mfma_f32_16x16x32_bf16(
                        af[i], bfr[j], acc[i][j], 0, 0, 0);
        }
        __syncthreads();
    }

    // ---- epilogue: +bias, *scale, cast bf16, store
    #pragma unroll
    for (int i = 0; i < 4; ++i) {
        #pragma unroll
        for (int j = 0; j < 4; ++j) {
            const int n_g = nblk * 128 + wn * 64 + j * 16 + (lane & 15);
            const float b = bias[wrow0 + n_g];
            #pragma unroll
            for (int r = 0; r < 4; ++r) {
                const size_t m_g = arow0 + wm * 64 + i * 16 + (lane >> 4) * 4 + r;
                out[m_g * D + n_g] = (bf16)((acc[i][j][r] + b) * scale);
            }
        }
    }
}

// ---------------------------------------------------------------------------
// Kernel 4: flash attention.  grid = 256 blocks = (b, h, qt), 4 waves/block,
// each wave owns 16 q rows.  KV chunk = 64.  Online softmax (exp2 domain,
// scale folded into Q).  V staged transposed in double-buffered LDS.
// ---------------------------------------------------------------------------
__global__ __launch_bounds__(256) void attn_kernel(
    const bf16* __restrict__ Qb, const bf16* __restrict__ Kb,
    const bf16* __restrict__ Vb, bf16* __restrict__ Ob)
{
    __shared__ bf16 Vt[2][32][72];   // V^T chunk, double buffered
    __shared__ bf16 Pl[4][16][72];   // per-wave P tile

    const int tid = threadIdx.x, lane = tid & 63, wid = tid >> 6;
    const int bid = blockIdx.x;
    const int b = bid >> 5, h = (bid >> 2) & 7, qt = bid & 3;

    // Q fragment (A operand), held in registers for the whole loop
    const int qrow = b * LQ_ + qt * 64 + wid * 16 + (lane & 15);
    const bf16x8 qf =
        *(const bf16x8*)&Qb[(size_t)qrow * D + h * HD + (lane >> 4) * 8];

    const size_t kvbase = (size_t)b * LS_;
    const f32x4 zero4 = (f32x4){0.f, 0.f, 0.f, 0.f};

    float m_run[4], l_run[4];
    f32x4 acc_o[2];
    #pragma unroll
    for (int r = 0; r < 4; ++r) { m_run[r] = -1e30f; l_run[r] = 0.f; }
    acc_o[0] = zero4; acc_o[1] = zero4;

    const int vrow = tid >> 2, vc = (tid & 3) * 8;

    for (int kc = 0; kc < LS_ / 64; ++kc) {
        const int k0 = kc * 64;
        const int buf = kc & 1;

        // ---- stage V^T chunk (64 k x 32 d -> Vt[32][64])
        const bf16x8 vv =
            *(const bf16x8*)&Vb[(kvbase + k0 + vrow) * D + h * HD + vc];
        #pragma unroll
        for (int j = 0; j < 8; ++j) Vt[buf][vc + j][vrow] = vv[j];
        __syncthreads();

        // ---- S = Q K^T (16 q x 64 k per wave); K frags straight from global
        f32x4 s[4];
        #pragma unroll
        for (int t = 0; t < 4; ++t) {
            const bf16x8 kf = *(const bf16x8*)
                &Kb[(kvbase + k0 + t * 16 + (lane & 15)) * D + h * HD + (lane >> 4) * 8];
            s[t] = __builtin_amdgcn_mfma_f32_16x16x32_bf16(qf, kf, zero4, 0, 0, 0);
        }

        // ---- online softmax, row r lives at C row (lane>>4)*4+r, col lane&15
        float p[4][4];
        #pragma unroll
        for (int r = 0; r < 4; ++r) {
            float mx = fmaxf(fmaxf(s[0][r], s[1][r]), fmaxf(s[2][r], s[3][r]));
            mx = fmaxf(mx, __shfl_xor(mx, 1));
            mx = fmaxf(mx, __shfl_xor(mx, 2));
            mx = fmaxf(mx, __shfl_xor(mx, 4));
            mx = fmaxf(mx, __shfl_xor(mx, 8));
            const float mn = fmaxf(m_run[r], mx);
            const float rs = exp2f(m_run[r] - mn);
            m_run[r] = mn;
            float sum = 0.f;
            #pragma unroll
            for (int t = 0; t < 4; ++t) { p[t][r] = exp2f(s[t][r] - mn); sum += p[t][r]; }
            sum += __shfl_xor(sum, 1);
            sum += __shfl_xor(sum, 2);
            sum += __shfl_xor(sum, 4);
            sum += __shfl_xor(sum, 8);
            l_run[r] = l_run[r] * rs + sum;
            acc_o[0][r] *= rs;
            acc_o[1][r] *= rs;
        }

        // ---- P -> LDS (per-wave private; same-wave in-order LDS, no barrier)
        #pragma unroll
        for (int t = 0; t < 4; ++t)
            #pragma unroll
            for (int r = 0; r < 4; ++r)
                Pl[wid][(lane >> 4) * 4 + r][t * 16 + (lane & 15)] = (bf16)p[t][r];

        // ---- O += P V
        #pragma unroll
        for (int ks = 0; ks < 2; ++ks) {
            const bf16x8 pa =
                *(const bf16x8*)&Pl[wid][lane & 15][ks * 32 + (lane >> 4) * 8];
            #pragma unroll
            for (int dt = 0; dt < 2; ++dt) {
                const bf16x8 vb = *(const bf16x8*)
                    &Vt[buf][dt * 16 + (lane & 15)][ks * 32 + (lane >> 4) * 8];
                acc_o[dt] = __builtin_amdgcn_mfma_f32_16x16x32_bf16(
                    pa, vb, acc_o[dt], 0, 0, 0);
            }
        }
    }

    // ---- normalize, store O (bf16)
    #pragma unroll
    for (int dt = 0; dt < 2; ++dt)
        #pragma unroll
        for (int r = 0; r < 4; ++r) {
            const size_t qg = (size_t)b * LQ_ + qt * 64 + wid * 16 + (lane >> 4) * 4 + r;
            Ob[qg * D + h * HD + dt * 16 + (lane & 15)] =
                (bf16)(acc_o[dt][r] / l_run[r]);
        }
}

// ---------------------------------------------------------------------------
// Kernel 5: output projection.  R[m][n] = sum_d O[m][d] * Wout[n][d] + b[n]
// grid (2, 16), tile 128x128, f32 output (residual+LN happens in kernel 6)
// ---------------------------------------------------------------------------
__global__ __launch_bounds__(256) void out_proj_kernel(
    const bf16* __restrict__ a, const bf16* __restrict__ wb,
    const float* __restrict__ bias, float* __restrict__ outR)
{
    __shared__ bf16 As[128][72];
    __shared__ bf16 Bs[128][72];
    const int tid = threadIdx.x, lane = tid & 63, wid = tid >> 6;
    const int wm = wid >> 1, wn = wid & 1;
    const int nblk = blockIdx.x, mblk = blockIdx.y;

    f32x4 acc[4][4];
    #pragma unroll
    for (int i = 0; i < 4; ++i)
        #pragma unroll
        for (int j = 0; j < 4; ++j) acc[i][j] = (f32x4){0.f, 0.f, 0.f, 0.f};

    for (int kk = 0; kk < 4; ++kk) {
        const int d0 = kk * 64;
        #pragma unroll
        for (int i = 0; i < 4; ++i) {
            const int idx = i * 256 + tid;
            const int r = idx >> 3, c = (idx & 7) * 8;
            *(bf16x8*)&As[r][c] =
                *(const bf16x8*)&a[(size_t)(mblk * 128 + r) * D + d0 + c];
            *(bf16x8*)&Bs[r][c] =
                *(const bf16x8*)&wb[(size_t)(nblk * 128 + r) * D + d0 + c];
        }
        __syncthreads();
        #pragma unroll
        for (int h2 = 0; h2 < 2; ++h2) {
            const int ko = h2 * 32 + (lane >> 4) * 8;
            bf16x8 af[4], bfr[4];
            #pragma unroll
            for (int i = 0; i < 4; ++i)
                af[i] = *(const bf16x8*)&As[wm * 64 + i * 16 + (lane & 15)][ko];
            #pragma unroll
            for (int j = 0; j < 4; ++j)
                bfr[j] = *(const bf16x8*)&Bs[wn * 64 + j * 16 + (lane & 15)][ko];
            #pragma unroll
            for (int i = 0; i < 4; ++i)
                #pragma unroll
                for (int j = 0; j < 4; ++j)
                    acc[i][j] = __builtin_amdgcn_mfma_f32_16x16x32_bf16(
                        af[i], bfr[j], acc[i][j], 0, 0, 0);
        }
        __syncthreads();
    }

    #pragma unroll
    for (int i = 0; i < 4; ++i)
        #pragma unroll
        for (int j = 0; j < 4; ++j) {
            const int n_g = nblk * 128 + wn * 64 + j * 16 + (lane & 15);
            const float b = bias[n_g];
            #pragma unroll
            for (int r = 0; r < 4; ++r) {
                const size_t m_g = (size_t)mblk * 128 + wm * 64 + i * 16 + (lane >> 4) * 4 + r;
                outR[m_g * D + n_g] = acc[i][j][r] + b;
            }
        }
}

// ---------------------------------------------------------------------------
// Kernel 6: residual + LayerNorm.  1 wave per 256-wide row, 4 rows/block.
// ---------------------------------------------------------------------------
__global__ __launch_bounds__(256) void ln_kernel(
    const float* __restrict__ Rb, const float* __restrict__ query,
    const float* __restrict__ lnw, const float* __restrict__ lnb,
    float* __restrict__ out)
{
    const int tid = threadIdx.x, lane = tid & 63, wid = tid >> 6;
    const size_t row = (size_t)blockIdx.x * 4 + wid;
    const float4 a = *(const float4*)&Rb[row * D + lane * 4];
    const float4 q = *(const float4*)&query[row * D + lane * 4];
    float4 r = make_float4(a.x + q.x, a.y + q.y, a.z + q.z, a.w + q.w);
    float s  = r.x + r.y + r.z + r.w;
    float sq = r.x * r.x + r.y * r.y + r.z * r.z + r.w * r.w;
    #pragma unroll
    for (int m = 1; m <= 32; m <<= 1) {
        s  += __shfl_xor(s,  m);
        sq += __shfl_xor(sq, m);
    }
    const float mean = s * (1.f / 256.f);
    const float var  = sq * (1.f / 256.f) - mean * mean;
    const float inv  = rsqrtf(var + 1e-5f);
    const float4 w = *(const float4*)&lnw[lane * 4];
    const float4 bb = *(const float4*)&lnb[lane * 4];
    float4 y;
    y.x = (r.x - mean) * inv * w.x + bb.x;
    y.y = (r.y - mean) * inv * w.y + bb.y;
    y.z = (r.z - mean) * inv * w.z + bb.z;
    y.w = (r.w - mean) * inv * w.w + bb.w;
    *(float4*)&out[row * D + lane * 4] = y;
}

// ---------------------------------------------------------------------------
extern "C" void kernel_launch(void* const* d_in, const int* in_sizes, int n_in,
                              void* d_out, int out_size, void* d_ws, size_t ws_size,
                              hipStream_t stream) {
    (void)in_sizes; (void)n_in; (void)out_size; (void)ws_size;
    const float* source    = (const float*)d_in[0];
    const float* query     = (const float*)d_in[1];
    const float* source_pe = (const float*)d_in[2];
    const float* query_pe  = (const float*)d_in[3];
    const float* in_proj_w = (const float*)d_in[4];
    const float* in_proj_b = (const float*)d_in[5];
    const float* out_w     = (const float*)d_in[6];
    const float* out_b     = (const float*)d_in[7];
    const float* ln_w      = (const float*)d_in[8];
    const float* ln_b      = (const float*)d_in[9];

    // workspace layout (bytes): ~36.5 MB total
    bf16* Wb   = (bf16*)d_ws;            // in_proj bf16 (768*256) ++ out_w bf16 (256*256)
    bf16* Win  = Wb;
    bf16* Wout = Wb + 768 * 256;
    bf16* Qb   = Wout + 256 * 256;       // 2048 x 256
    bf16* Kb   = Qb + (size_t)MQ * D;    // 32768 x 256
    bf16* Vb   = Kb + (size_t)MS * D;    // 32768 x 256
    bf16* Ob   = Vb + (size_t)MS * D;    // 2048 x 256
    float* Rb  = (float*)(Ob + (size_t)MQ * D);  // 2048 x 256 f32
    float* outp = (float*)d_out;

    cast_weights<<<dim3(256), dim3(256), 0, stream>>>(in_proj_w, out_w, Wb);
    proj_kernel<false><<<dim3(4, 256), dim3(256), 0, stream>>>(
        source, source_pe, Win, in_proj_b, Kb, Vb, 1.0f);
    proj_kernel<true><<<dim3(2, 16), dim3(256), 0, stream>>>(
        query, query_pe, Win, in_proj_b, Qb, Qb, QSCALE);
    attn_kernel<<<dim3(256), dim3(256), 0, stream>>>(Qb, Kb, Vb, Ob);
    out_proj_kernel<<<dim3(2, 16), dim3(256), 0, stream>>>(Ob, Wout, out_b, Rb);
    ln_kernel<<<dim3(512), dim3(256), 0, stream>>>(Rb, query, ln_w, ln_b, outp);
}

// Round 2
// 140.155 us; speedup vs baseline: 1.5310x; 1.5310x over previous
//
#include <hip/hip_runtime.h>
#include <hip/hip_bf16.h>

typedef __bf16 bf16;
typedef __bf16 bf16x4 __attribute__((ext_vector_type(4)));
typedef __bf16 bf16x8 __attribute__((ext_vector_type(8)));
typedef float f32x4 __attribute__((ext_vector_type(4)));

#define D 256          // embed dim
#define NHEAD 8
#define HD 32          // head dim
#define NB_ 8
#define LQ_ 256
#define LS_ 4096
#define MQ (NB_ * LQ_)   // 2048
#define MS (NB_ * LS_)   // 32768

// softmax scale folded into Q projection: hd^-0.5 * log2(e)
#define QSCALE 0.25500527f

// ---------------------------------------------------------------------------
// Kernel 1: cast in_proj_w (768x256) ++ out_w (256x256) to bf16 (contiguous)
// ---------------------------------------------------------------------------
__global__ __launch_bounds__(256) void cast_weights(
    const float* __restrict__ w_in, const float* __restrict__ w_out,
    bf16* __restrict__ wb)
{
    const int idx = blockIdx.x * 256 + threadIdx.x;   // float4 index, 65536 total
    const int n_in4 = (768 * 256) / 4;                 // 49152
    float4 v;
    if (idx < n_in4) v = ((const float4*)w_in)[idx];
    else             v = ((const float4*)w_out)[idx - n_in4];
    bf16x4 o;
    o[0] = (bf16)v.x; o[1] = (bf16)v.y; o[2] = (bf16)v.z; o[3] = (bf16)v.w;
    *(bf16x4*)&wb[(size_t)idx * 4] = o;
}

// ---------------------------------------------------------------------------
// Kernel 2/3: input projection GEMM.  C[m][n] = sum_d A[m][d] * W[n][d] + b[n]
// ---------------------------------------------------------------------------
template<bool IS_Q>
__global__ __launch_bounds__(256) void proj_kernel(
    const float* __restrict__ x, const float* __restrict__ pe,
    const bf16* __restrict__ wb, const float* __restrict__ bias,
    bf16* __restrict__ outK, bf16* __restrict__ outV, float scale)
{
    __shared__ bf16 As[128][72];
    __shared__ bf16 Bs[128][72];
    const int tid = threadIdx.x;
    const int lane = tid & 63, wid = tid >> 6;
    const int wm = wid >> 1, wn = wid & 1;

    const int by = blockIdx.x;
    const int mblk = blockIdx.y;

    bool addpe; int wrow0, nblk; bf16* out;
    if (IS_Q) { addpe = true; wrow0 = 0; nblk = by; out = outK; }
    else {
        const bool isK = (by < 2);
        addpe = isK; wrow0 = isK ? 256 : 512; nblk = by & 1;
        out = isK ? outK : outV;
    }

    f32x4 acc[4][4];
    #pragma unroll
    for (int i = 0; i < 4; ++i)
        #pragma unroll
        for (int j = 0; j < 4; ++j) acc[i][j] = (f32x4){0.f, 0.f, 0.f, 0.f};

    const size_t arow0 = (size_t)mblk * 128;

    for (int kk = 0; kk < 4; ++kk) {
        const int d0 = kk * 64;
        #pragma unroll
        for (int i = 0; i < 8; ++i) {
            const int idx = i * 256 + tid;       // 0..2047 float4 chunks
            const int r = idx >> 4, c = (idx & 15) * 4;
            const size_t g = (arow0 + r) * D + d0 + c;
            float4 v = *(const float4*)&x[g];
            if (addpe) {
                const float4 p = *(const float4*)&pe[g];
                v.x += p.x; v.y += p.y; v.z += p.z; v.w += p.w;
            }
            bf16x4 o;
            o[0] = (bf16)v.x; o[1] = (bf16)v.y; o[2] = (bf16)v.z; o[3] = (bf16)v.w;
            *(bf16x4*)&As[r][c] = o;
        }
        #pragma unroll
        for (int i = 0; i < 4; ++i) {
            const int idx = i * 256 + tid;       // 0..1023 16B chunks
            const int r = idx >> 3, c = (idx & 7) * 8;
            *(bf16x8*)&Bs[r][c] =
                *(const bf16x8*)&wb[(size_t)(wrow0 + nblk * 128 + r) * D + d0 + c];
        }
        __syncthreads();

        #pragma unroll
        for (int h2 = 0; h2 < 2; ++h2) {
            const int ko = h2 * 32 + (lane >> 4) * 8;
            bf16x8 af[4], bfr[4];
            #pragma unroll
            for (int i = 0; i < 4; ++i)
                af[i] = *(const bf16x8*)&As[wm * 64 + i * 16 + (lane & 15)][ko];
            #pragma unroll
            for (int j = 0; j < 4; ++j)
                bfr[j] = *(const bf16x8*)&Bs[wn * 64 + j * 16 + (lane & 15)][ko];
            #pragma unroll
            for (int i = 0; i < 4; ++i)
                #pragma unroll
                for (int j = 0; j < 4; ++j)
                    acc[i][j] = __builtin_amdgcn_mfma_f32_16x16x32_bf16(
                        af[i], bfr[j], acc[i][j], 0, 0, 0);
        }
        __syncthreads();
    }

    #pragma unroll
    for (int i = 0; i < 4; ++i) {
        #pragma unroll
        for (int j = 0; j < 4; ++j) {
            const int n_g = nblk * 128 + wn * 64 + j * 16 + (lane & 15);
            const float b = bias[wrow0 + n_g];
            #pragma unroll
            for (int r = 0; r < 4; ++r) {
                const size_t m_g = arow0 + wm * 64 + i * 16 + (lane >> 4) * 4 + r;
                out[m_g * D + n_g] = (bf16)((acc[i][j][r] + b) * scale);
            }
        }
    }
}

// ---------------------------------------------------------------------------
// Kernel 4: split-KV flash attention.
// grid = 256*S blocks; bid = inner*8 + h  (=> XCD == h for L2 locality)
// inner = b*(S*4) + split*4 + qt.  4 waves/block, wave owns 16 q rows.
// Writes UNNORMALIZED partials (m, l, acc) per (task, split).
// task = (b*8+h)*16 + qt*4 + wid.
// ---------------------------------------------------------------------------
template<int S>
__global__ __launch_bounds__(256, 8) void attn_kernel(
    const bf16* __restrict__ Qb, const bf16* __restrict__ Kb,
    const bf16* __restrict__ Vb,
    float* __restrict__ accp, float2* __restrict__ mlp)
{
    __shared__ bf16 Vt[2][32][72];   // V^T chunk, double buffered, XOR-swizzled
    __shared__ bf16 Pl[4][16][72];   // per-wave P tile, XOR-swizzled

    const int tid = threadIdx.x, lane = tid & 63, wid = tid >> 6;
    const int bid = blockIdx.x;
    const int h = bid & 7;
    const int inner = bid >> 3;
    const int b = inner / (S * 4);
    const int rem = inner % (S * 4);
    const int split = rem >> 2, qt = rem & 3;

    // Q fragment (A operand), registers for the whole loop
    const int qrow = b * LQ_ + qt * 64 + wid * 16 + (lane & 15);
    const bf16x8 qf =
        *(const bf16x8*)&Qb[(size_t)qrow * D + h * HD + (lane >> 4) * 8];

    const size_t kvbase = (size_t)b * LS_;
    const int kv0 = split * (LS_ / S);
    const f32x4 zero4 = (f32x4){0.f, 0.f, 0.f, 0.f};

    float m_run[4], l_run[4];
    f32x4 acc_o[2];
    #pragma unroll
    for (int r = 0; r < 4; ++r) { m_run[r] = -1e30f; l_run[r] = 0.f; }
    acc_o[0] = zero4; acc_o[1] = zero4;

    const int vrow = tid >> 2;           // k within chunk (0..63)
    const int vc = (tid & 3) * 8;        // d base (0,8,16,24)

    for (int kc = 0; kc < LS_ / S / 64; ++kc) {
        const int k0 = kv0 + kc * 64;
        const int buf = kc & 1;

        // ---- stage V^T chunk (64 k x 32 d), swizzled: k' = k ^ ((d>>3)<<4)
        const bf16x8 vv =
            *(const bf16x8*)&Vb[(kvbase + k0 + vrow) * D + h * HD + vc];
        #pragma unroll
        for (int j = 0; j < 8; ++j) {
            const int d = vc + j;
            Vt[buf][d][vrow ^ ((d >> 3) << 4)] = vv[j];
        }
        __syncthreads();

        // ---- S = Q K^T (16 q x 64 k per wave); K frags straight from global
        f32x4 s[4];
        #pragma unroll
        for (int t = 0; t < 4; ++t) {
            const bf16x8 kf = *(const bf16x8*)
                &Kb[(kvbase + k0 + t * 16 + (lane & 15)) * D + h * HD + (lane >> 4) * 8];
            s[t] = __builtin_amdgcn_mfma_f32_16x16x32_bf16(qf, kf, zero4, 0, 0, 0);
        }

        // ---- online softmax (exp2 domain)
        float p[4][4];
        #pragma unroll
        for (int r = 0; r < 4; ++r) {
            float mx = fmaxf(fmaxf(s[0][r], s[1][r]), fmaxf(s[2][r], s[3][r]));
            mx = fmaxf(mx, __shfl_xor(mx, 1));
            mx = fmaxf(mx, __shfl_xor(mx, 2));
            mx = fmaxf(mx, __shfl_xor(mx, 4));
            mx = fmaxf(mx, __shfl_xor(mx, 8));
            const float mn = fmaxf(m_run[r], mx);
            const float rs = exp2f(m_run[r] - mn);
            m_run[r] = mn;
            float sum = 0.f;
            #pragma unroll
            for (int t = 0; t < 4; ++t) { p[t][r] = exp2f(s[t][r] - mn); sum += p[t][r]; }
            sum += __shfl_xor(sum, 1);
            sum += __shfl_xor(sum, 2);
            sum += __shfl_xor(sum, 4);
            sum += __shfl_xor(sum, 8);
            l_run[r] = l_run[r] * rs + sum;
            acc_o[0][r] *= rs;
            acc_o[1][r] *= rs;
        }

        // ---- P -> LDS (per-wave private), swizzled: col' = col ^ ((row>>2)<<3)
        #pragma unroll
        for (int t = 0; t < 4; ++t)
            #pragma unroll
            for (int r = 0; r < 4; ++r)
                Pl[wid][(lane >> 4) * 4 + r][(t * 16 + (lane & 15)) ^ ((lane >> 4) << 3)]
                    = (bf16)p[t][r];

        // ---- O += P V
        #pragma unroll
        for (int ks = 0; ks < 2; ++ks) {
            const int prow = lane & 15;
            const bf16x8 pa = *(const bf16x8*)
                &Pl[wid][prow][(ks * 32 + (lane >> 4) * 8) ^ ((prow >> 2) << 3)];
            #pragma unroll
            for (int dt = 0; dt < 2; ++dt) {
                const int d = dt * 16 + (lane & 15);
                const bf16x8 vb = *(const bf16x8*)
                    &Vt[buf][d][(ks * 32 + (lane >> 4) * 8) ^ ((d >> 3) << 4)];
                acc_o[dt] = __builtin_amdgcn_mfma_f32_16x16x32_bf16(
                    pa, vb, acc_o[dt], 0, 0, 0);
            }
        }
    }

    // ---- store unnormalized partial
    const int task = (b * 8 + h) * 16 + qt * 4 + wid;
    const int pbase = (task * S + split) * 16;
    #pragma unroll
    for (int dt = 0; dt < 2; ++dt)
        #pragma unroll
        for (int r = 0; r < 4; ++r) {
            const int q = (lane >> 4) * 4 + r;
            accp[(size_t)(pbase + q) * 32 + dt * 16 + (lane & 15)] = acc_o[dt][r];
        }
    if ((lane & 15) == 0) {
        #pragma unroll
        for (int r = 0; r < 4; ++r) {
            const int q = (lane >> 4) * 4 + r;
            mlp[pbase + q] = make_float2(m_run[r], l_run[r]);
        }
    }
}

// ---------------------------------------------------------------------------
// Kernel 4b: combine split partials.  1 wave per task (16 q x 32 d).
// ---------------------------------------------------------------------------
template<int S>
__global__ __launch_bounds__(256) void attn_combine(
    const float* __restrict__ accp, const float2* __restrict__ mlp,
    bf16* __restrict__ Ob)
{
    const int tid = threadIdx.x, lane = tid & 63, wid = tid >> 6;
    const int task = blockIdx.x * 4 + wid;
    const int d = lane & 31, rh = lane >> 5;
    const int b = task >> 7, h = (task >> 4) & 7, qg = task & 15;

    #pragma unroll
    for (int qi = 0; qi < 8; ++qi) {
        const int q = rh * 8 + qi;
        float ms[S], ls[S];
        float m_g = -1e30f;
        #pragma unroll
        for (int s = 0; s < S; ++s) {
            const float2 ml = mlp[(task * S + s) * 16 + q];
            ms[s] = ml.x; ls[s] = ml.y;
            m_g = fmaxf(m_g, ms[s]);
        }
        float l_g = 0.f, o = 0.f;
        #pragma unroll
        for (int s = 0; s < S; ++s) {
            const float f = exp2f(ms[s] - m_g);
            l_g += ls[s] * f;
            o += accp[(size_t)((task * S + s) * 16 + q) * 32 + d] * f;
        }
        const size_t row = (size_t)b * LQ_ + qg * 16 + q;
        Ob[row * D + h * HD + d] = (bf16)(o / l_g);
    }
}

// ---------------------------------------------------------------------------
// Kernel 5: output projection (f32 out; residual+LN in kernel 6)
// ---------------------------------------------------------------------------
__global__ __launch_bounds__(256) void out_proj_kernel(
    const bf16* __restrict__ a, const bf16* __restrict__ wb,
    const float* __restrict__ bias, float* __restrict__ outR)
{
    __shared__ bf16 As[128][72];
    __shared__ bf16 Bs[128][72];
    const int tid = threadIdx.x, lane = tid & 63, wid = tid >> 6;
    const int wm = wid >> 1, wn = wid & 1;
    const int nblk = blockIdx.x, mblk = blockIdx.y;

    f32x4 acc[4][4];
    #pragma unroll
    for (int i = 0; i < 4; ++i)
        #pragma unroll
        for (int j = 0; j < 4; ++j) acc[i][j] = (f32x4){0.f, 0.f, 0.f, 0.f};

    for (int kk = 0; kk < 4; ++kk) {
        const int d0 = kk * 64;
        #pragma unroll
        for (int i = 0; i < 4; ++i) {
            const int idx = i * 256 + tid;
            const int r = idx >> 3, c = (idx & 7) * 8;
            *(bf16x8*)&As[r][c] =
                *(const bf16x8*)&a[(size_t)(mblk * 128 + r) * D + d0 + c];
            *(bf16x8*)&Bs[r][c] =
                *(const bf16x8*)&wb[(size_t)(nblk * 128 + r) * D + d0 + c];
        }
        __syncthreads();
        #pragma unroll
        for (int h2 = 0; h2 < 2; ++h2) {
            const int ko = h2 * 32 + (lane >> 4) * 8;
            bf16x8 af[4], bfr[4];
            #pragma unroll
            for (int i = 0; i < 4; ++i)
                af[i] = *(const bf16x8*)&As[wm * 64 + i * 16 + (lane & 15)][ko];
            #pragma unroll
            for (int j = 0; j < 4; ++j)
                bfr[j] = *(const bf16x8*)&Bs[wn * 64 + j * 16 + (lane & 15)][ko];
            #pragma unroll
            for (int i = 0; i < 4; ++i)
                #pragma unroll
                for (int j = 0; j < 4; ++j)
                    acc[i][j] = __builtin_amdgcn_mfma_f32_16x16x32_bf16(
                        af[i], bfr[j], acc[i][j], 0, 0, 0);
        }
        __syncthreads();
    }

    #pragma unroll
    for (int i = 0; i < 4; ++i)
        #pragma unroll
        for (int j = 0; j < 4; ++j) {
            const int n_g = nblk * 128 + wn * 64 + j * 16 + (lane & 15);
            const float b = bias[n_g];
            #pragma unroll
            for (int r = 0; r < 4; ++r) {
                const size_t m_g = (size_t)mblk * 128 + wm * 64 + i * 16 + (lane >> 4) * 4 + r;
                outR[m_g * D + n_g] = acc[i][j][r] + b;
            }
        }
}

// ---------------------------------------------------------------------------
// Kernel 6: residual + LayerNorm.  1 wave per 256-wide row, 4 rows/block.
// ---------------------------------------------------------------------------
__global__ __launch_bounds__(256) void ln_kernel(
    const float* __restrict__ Rb, const float* __restrict__ query,
    const float* __restrict__ lnw, const float* __restrict__ lnb,
    float* __restrict__ out)
{
    const int tid = threadIdx.x, lane = tid & 63, wid = tid >> 6;
    const size_t row = (size_t)blockIdx.x * 4 + wid;
    const float4 a = *(const float4*)&Rb[row * D + lane * 4];
    const float4 q = *(const float4*)&query[row * D + lane * 4];
    float4 r = make_float4(a.x + q.x, a.y + q.y, a.z + q.z, a.w + q.w);
    float s  = r.x + r.y + r.z + r.w;
    float sq = r.x * r.x + r.y * r.y + r.z * r.z + r.w * r.w;
    #pragma unroll
    for (int m = 1; m <= 32; m <<= 1) {
        s  += __shfl_xor(s,  m);
        sq += __shfl_xor(sq, m);
    }
    const float mean = s * (1.f / 256.f);
    const float var  = sq * (1.f / 256.f) - mean * mean;
    const float inv  = rsqrtf(var + 1e-5f);
    const float4 w = *(const float4*)&lnw[lane * 4];
    const float4 bb = *(const float4*)&lnb[lane * 4];
    float4 y;
    y.x = (r.x - mean) * inv * w.x + bb.x;
    y.y = (r.y - mean) * inv * w.y + bb.y;
    y.z = (r.z - mean) * inv * w.z + bb.z;
    y.w = (r.w - mean) * inv * w.w + bb.w;
    *(float4*)&out[row * D + lane * 4] = y;
}

// ---------------------------------------------------------------------------
extern "C" void kernel_launch(void* const* d_in, const int* in_sizes, int n_in,
                              void* d_out, int out_size, void* d_ws, size_t ws_size,
                              hipStream_t stream) {
    (void)in_sizes; (void)n_in; (void)out_size;
    const float* source    = (const float*)d_in[0];
    const float* query     = (const float*)d_in[1];
    const float* source_pe = (const float*)d_in[2];
    const float* query_pe  = (const float*)d_in[3];
    const float* in_proj_w = (const float*)d_in[4];
    const float* in_proj_b = (const float*)d_in[5];
    const float* out_w     = (const float*)d_in[6];
    const float* out_b     = (const float*)d_in[7];
    const float* ln_w      = (const float*)d_in[8];
    const float* ln_b      = (const float*)d_in[9];

    // workspace layout
    bf16* Wb   = (bf16*)d_ws;            // (768+256)*256 bf16 = 512KB
    bf16* Win  = Wb;
    bf16* Wout = Wb + 768 * 256;
    bf16* Qb   = Wout + 256 * 256;       // 2048 x 256 bf16
    bf16* Kb   = Qb + (size_t)MQ * D;    // 32768 x 256 bf16
    bf16* Vb   = Kb + (size_t)MS * D;    // 32768 x 256 bf16
    bf16* Ob   = Vb + (size_t)MS * D;    // 2048 x 256 bf16
    float* Rb  = (float*)(Ob + (size_t)MQ * D);  // 2048 x 256 f32
    float* accp = Rb + (size_t)MQ * D;   // partial acc: 1024*S*16*32 f32
    const size_t base_bytes = (char*)accp - (char*)d_ws;   // 36.5 MB
    float* outp = (float*)d_out;

    auto need = [&](int S) -> size_t {
        return base_bytes + (size_t)1024 * S * 16 * 32 * 4   // accp
                          + (size_t)1024 * S * 16 * 8;       // mlp
    };

    cast_weights<<<dim3(256), dim3(256), 0, stream>>>(in_proj_w, out_w, Wb);
    proj_kernel<false><<<dim3(4, 256), dim3(256), 0, stream>>>(
        source, source_pe, Win, in_proj_b, Kb, Vb, 1.0f);
    proj_kernel<true><<<dim3(2, 16), dim3(256), 0, stream>>>(
        query, query_pe, Win, in_proj_b, Qb, Qb, QSCALE);

    if (ws_size >= need(8)) {
        constexpr int S = 8;
        float2* mlp = (float2*)(accp + (size_t)1024 * S * 16 * 32);
        attn_kernel<S><<<dim3(256 * S), dim3(256), 0, stream>>>(Qb, Kb, Vb, accp, mlp);
        attn_combine<S><<<dim3(256), dim3(256), 0, stream>>>(accp, mlp, Ob);
    } else if (ws_size >= need(4)) {
        constexpr int S = 4;
        float2* mlp = (float2*)(accp + (size_t)1024 * S * 16 * 32);
        attn_kernel<S><<<dim3(256 * S), dim3(256), 0, stream>>>(Qb, Kb, Vb, accp, mlp);
        attn_combine<S><<<dim3(256), dim3(256), 0, stream>>>(accp, mlp, Ob);
    } else {
        constexpr int S = 2;
        float2* mlp = (float2*)(accp + (size_t)1024 * S * 16 * 32);
        attn_kernel<S><<<dim3(256 * S), dim3(256), 0, stream>>>(Qb, Kb, Vb, accp, mlp);
        attn_combine<S><<<dim3(256), dim3(256), 0, stream>>>(accp, mlp, Ob);
    }

    out_proj_kernel<<<dim3(2, 16), dim3(256), 0, stream>>>(Ob, Wout, out_b, Rb);
    ln_kernel<<<dim3(512), dim3(256), 0, stream>>>(Rb, query, ln_w, ln_b, outp);
}